// Round 3
// baseline (2646.653 us; speedup 1.0000x reference)
//
#include <hip/hip_runtime.h>
#include <cstdint>

#define NOUTC 131072
#define NINC  16384

using uint = unsigned int;

__device__ __forceinline__ uint fkey(float v){
  uint u = __float_as_uint(v);
  return (u & 0x80000000u) ? ~u : (u | 0x80000000u);
}

// 512-block grids: XCD-chunked swizzle (nwg=512, 512/8=64 blocks per XCD chunk)
__device__ __forceinline__ int swz_row(int bx, int tid) {
  return ((((bx & 7) << 6) | (bx >> 3)) << 8) + tid;
}

// ---------------------------------------------------------------------------
// c0: out[n] = relu( sum_k feats[nbr[k][n]] @ W[k] + b ),  64 -> 64, 27 taps.
// Row-per-thread, weights via scalar loads (wave-uniform), acc in VGPRs.
// ---------------------------------------------------------------------------
__global__ __launch_bounds__(256)
void conv_c0_kernel(const float* __restrict__ feats, const int* __restrict__ nbr,
                    const float* __restrict__ Wg, const float* __restrict__ bias,
                    float* __restrict__ outp)
{
  const int n = swz_row(blockIdx.x, threadIdx.x);
  float acc[64];
  #pragma unroll
  for (int i = 0; i < 64; ++i) acc[i] = 0.f;

  for (int k = 0; k < 27; ++k) {
    const int idx = nbr[(size_t)k * NOUTC + n];
    const float4* src = reinterpret_cast<const float4*>(feats + (size_t)idx * 64);
    const float* w = Wg + k * 4096;
    #pragma unroll 1
    for (int c = 0; c < 4; ++c) {
      float4 a0 = src[c * 4 + 0], a1 = src[c * 4 + 1];
      float4 a2 = src[c * 4 + 2], a3 = src[c * 4 + 3];
      float fr[16];
      fr[0]=a0.x; fr[1]=a0.y; fr[2]=a0.z; fr[3]=a0.w;
      fr[4]=a1.x; fr[5]=a1.y; fr[6]=a1.z; fr[7]=a1.w;
      fr[8]=a2.x; fr[9]=a2.y; fr[10]=a2.z; fr[11]=a2.w;
      fr[12]=a3.x; fr[13]=a3.y; fr[14]=a3.z; fr[15]=a3.w;
      const float* wc = w + c * 1024;
      #pragma unroll
      for (int u = 0; u < 16; ++u)
        #pragma unroll
        for (int co = 0; co < 64; ++co)
          acc[co] = fmaf(fr[u], wc[u * 64 + co], acc[co]);
    }
  }

  float* dst = outp + (size_t)n * 64;
  #pragma unroll
  for (int j = 0; j < 16; ++j) {
    float4 o;
    float v0 = acc[4*j+0] + bias[4*j+0]; o.x = v0 > 0.f ? v0 : 0.f;
    float v1 = acc[4*j+1] + bias[4*j+1]; o.y = v1 > 0.f ? v1 : 0.f;
    float v2 = acc[4*j+2] + bias[4*j+2]; o.z = v2 > 0.f ? v2 : 0.f;
    float v3 = acc[4*j+3] + bias[4*j+3]; o.w = v3 > 0.f ? v3 : 0.f;
    reinterpret_cast<float4*>(dst)[j] = o;
  }
}

// ---------------------------------------------------------------------------
// A: t0 = relu(spconv(cur, W00, b00))  [64->16, 27 taps]
//    t1 = relu(cur @ W10 + b10)        [1x1, fused at k==13 (self tap)]
// ---------------------------------------------------------------------------
__global__ __launch_bounds__(256)
void conv_A_kernel(const float* __restrict__ feats, const int* __restrict__ nbr,
                   const float* __restrict__ W00i, const float* __restrict__ b00i,
                   const float* __restrict__ W10i, const float* __restrict__ b10i,
                   float* __restrict__ t0, float* __restrict__ t1)
{
  const int n = swz_row(blockIdx.x, threadIdx.x);
  float acc0[16], acc1[16];
  #pragma unroll
  for (int i = 0; i < 16; ++i) { acc0[i] = 0.f; acc1[i] = 0.f; }

  for (int k = 0; k < 27; ++k) {
    const int idx = nbr[(size_t)k * NOUTC + n];
    const float4* src = reinterpret_cast<const float4*>(feats + (size_t)idx * 64);
    const float* w0 = W00i + k * 1024;
    #pragma unroll 1
    for (int c = 0; c < 4; ++c) {
      float4 a0 = src[c * 4 + 0], a1 = src[c * 4 + 1];
      float4 a2 = src[c * 4 + 2], a3 = src[c * 4 + 3];
      float fr[16];
      fr[0]=a0.x; fr[1]=a0.y; fr[2]=a0.z; fr[3]=a0.w;
      fr[4]=a1.x; fr[5]=a1.y; fr[6]=a1.z; fr[7]=a1.w;
      fr[8]=a2.x; fr[9]=a2.y; fr[10]=a2.z; fr[11]=a2.w;
      fr[12]=a3.x; fr[13]=a3.y; fr[14]=a3.z; fr[15]=a3.w;
      #pragma unroll
      for (int u = 0; u < 16; ++u)
        #pragma unroll
        for (int co = 0; co < 16; ++co)
          acc0[co] = fmaf(fr[u], w0[(c * 16 + u) * 16 + co], acc0[co]);
      if (k == 13) {
        #pragma unroll
        for (int u = 0; u < 16; ++u)
          #pragma unroll
          for (int co = 0; co < 16; ++co)
            acc1[co] = fmaf(fr[u], W10i[(c * 16 + u) * 16 + co], acc1[co]);
      }
    }
  }

  float* d0 = t0 + (size_t)n * 16;
  float* d1 = t1 + (size_t)n * 16;
  #pragma unroll
  for (int j = 0; j < 4; ++j) {
    float4 o0, o1;
    float v;
    v = acc0[4*j+0] + b00i[4*j+0]; o0.x = v > 0.f ? v : 0.f;
    v = acc0[4*j+1] + b00i[4*j+1]; o0.y = v > 0.f ? v : 0.f;
    v = acc0[4*j+2] + b00i[4*j+2]; o0.z = v > 0.f ? v : 0.f;
    v = acc0[4*j+3] + b00i[4*j+3]; o0.w = v > 0.f ? v : 0.f;
    v = acc1[4*j+0] + b10i[4*j+0]; o1.x = v > 0.f ? v : 0.f;
    v = acc1[4*j+1] + b10i[4*j+1]; o1.y = v > 0.f ? v : 0.f;
    v = acc1[4*j+2] + b10i[4*j+2]; o1.z = v > 0.f ? v : 0.f;
    v = acc1[4*j+3] + b10i[4*j+3]; o1.w = v > 0.f ? v : 0.f;
    reinterpret_cast<float4*>(d0)[j] = o0;
    reinterpret_cast<float4*>(d1)[j] = o1;
  }
}

// ---------------------------------------------------------------------------
// B: o0 = spconv(t0, W01, b01) [16->32, 27 taps]
//    t2 = relu(spconv(t1, W11, b11)) [16->16, 27 taps]
//    o1 = t2 @ W12 + b12 [1x1, in-register]
//    nxt[n] = concat(o0, o1) + cur[n]
// ---------------------------------------------------------------------------
__global__ __launch_bounds__(256)
void conv_B_kernel(const float* __restrict__ t0, const float* __restrict__ t1,
                   const float* __restrict__ cur, const int* __restrict__ nbr,
                   const float* __restrict__ W01i, const float* __restrict__ b01i,
                   const float* __restrict__ W11i, const float* __restrict__ b11i,
                   const float* __restrict__ W12i, const float* __restrict__ b12i,
                   float* __restrict__ nxt)
{
  const int n = swz_row(blockIdx.x, threadIdx.x);
  float acc01[32], acc11[16];
  #pragma unroll
  for (int i = 0; i < 32; ++i) acc01[i] = 0.f;
  #pragma unroll
  for (int i = 0; i < 16; ++i) acc11[i] = 0.f;

  for (int k = 0; k < 27; ++k) {
    const int idx = nbr[(size_t)k * NOUTC + n];
    const float4* s0 = reinterpret_cast<const float4*>(t0 + (size_t)idx * 16);
    const float4* s1 = reinterpret_cast<const float4*>(t1 + (size_t)idx * 16);
    float4 a0 = s0[0], a1 = s0[1], a2 = s0[2], a3 = s0[3];
    float4 c0 = s1[0], c1 = s1[1], c2 = s1[2], c3 = s1[3];
    float f0[16], f1[16];
    f0[0]=a0.x; f0[1]=a0.y; f0[2]=a0.z; f0[3]=a0.w;
    f0[4]=a1.x; f0[5]=a1.y; f0[6]=a1.z; f0[7]=a1.w;
    f0[8]=a2.x; f0[9]=a2.y; f0[10]=a2.z; f0[11]=a2.w;
    f0[12]=a3.x; f0[13]=a3.y; f0[14]=a3.z; f0[15]=a3.w;
    f1[0]=c0.x; f1[1]=c0.y; f1[2]=c0.z; f1[3]=c0.w;
    f1[4]=c1.x; f1[5]=c1.y; f1[6]=c1.z; f1[7]=c1.w;
    f1[8]=c2.x; f1[9]=c2.y; f1[10]=c2.z; f1[11]=c2.w;
    f1[12]=c3.x; f1[13]=c3.y; f1[14]=c3.z; f1[15]=c3.w;
    const float* w01 = W01i + k * 512;
    const float* w11 = W11i + k * 256;
    #pragma unroll
    for (int u = 0; u < 16; ++u)
      #pragma unroll
      for (int co = 0; co < 32; ++co)
        acc01[co] = fmaf(f0[u], w01[u * 32 + co], acc01[co]);
    #pragma unroll
    for (int u = 0; u < 16; ++u)
      #pragma unroll
      for (int co = 0; co < 16; ++co)
        acc11[co] = fmaf(f1[u], w11[u * 16 + co], acc11[co]);
  }

  // t2 = relu(acc11 + b11); o1 = t2 @ W12 + b12
  float t2[16];
  #pragma unroll
  for (int u = 0; u < 16; ++u) {
    float v = acc11[u] + b11i[u];
    t2[u] = v > 0.f ? v : 0.f;
  }
  float acc12[32];
  #pragma unroll
  for (int co = 0; co < 32; ++co) acc12[co] = b12i[co];
  #pragma unroll
  for (int u = 0; u < 16; ++u)
    #pragma unroll
    for (int co = 0; co < 32; ++co)
      acc12[co] = fmaf(t2[u], W12i[u * 32 + co], acc12[co]);

  const float4* rs = reinterpret_cast<const float4*>(cur + (size_t)n * 64);
  float* dst = nxt + (size_t)n * 64;
  #pragma unroll
  for (int j = 0; j < 8; ++j) {
    float4 r = rs[j];
    float4 o;
    o.x = acc01[4*j+0] + b01i[4*j+0] + r.x;
    o.y = acc01[4*j+1] + b01i[4*j+1] + r.y;
    o.z = acc01[4*j+2] + b01i[4*j+2] + r.z;
    o.w = acc01[4*j+3] + b01i[4*j+3] + r.w;
    reinterpret_cast<float4*>(dst)[j] = o;
  }
  #pragma unroll
  for (int j = 0; j < 8; ++j) {
    float4 r = rs[8 + j];
    float4 o;
    o.x = acc12[4*j+0] + r.x;
    o.y = acc12[4*j+1] + r.y;
    o.z = acc12[4*j+2] + r.z;
    o.w = acc12[4*j+3] + r.w;
    reinterpret_cast<float4*>(dst)[8 + j] = o;
  }
}

// ---------------------------------------------------------------------------
// upsample: fa[(n*8+k)*64+:] = relu(x[n] @ Wup[k] + bup); uniform k per block
// ---------------------------------------------------------------------------
__global__ __launch_bounds__(256)
void up2_kernel(const float* __restrict__ x, const float* __restrict__ Wup,
                const float* __restrict__ bup, float* __restrict__ outp)
{
  const int k = blockIdx.x & 7;
  const int n = (blockIdx.x >> 3) * 256 + threadIdx.x;  // n < 16384
  const float4* src = reinterpret_cast<const float4*>(x + (size_t)n * 64);
  const float* w = Wup + k * 4096;
  float acc[64];
  #pragma unroll
  for (int i = 0; i < 64; ++i) acc[i] = 0.f;
  #pragma unroll 1
  for (int c = 0; c < 4; ++c) {
    float4 a0 = src[c * 4 + 0], a1 = src[c * 4 + 1];
    float4 a2 = src[c * 4 + 2], a3 = src[c * 4 + 3];
    float fr[16];
    fr[0]=a0.x; fr[1]=a0.y; fr[2]=a0.z; fr[3]=a0.w;
    fr[4]=a1.x; fr[5]=a1.y; fr[6]=a1.z; fr[7]=a1.w;
    fr[8]=a2.x; fr[9]=a2.y; fr[10]=a2.z; fr[11]=a2.w;
    fr[12]=a3.x; fr[13]=a3.y; fr[14]=a3.z; fr[15]=a3.w;
    const float* wc = w + c * 1024;
    #pragma unroll
    for (int u = 0; u < 16; ++u)
      #pragma unroll
      for (int co = 0; co < 64; ++co)
        acc[co] = fmaf(fr[u], wc[u * 64 + co], acc[co]);
  }
  float* dst = outp + ((size_t)n * 8 + k) * 64;
  #pragma unroll
  for (int j = 0; j < 16; ++j) {
    float4 o;
    float v0 = acc[4*j+0] + bup[4*j+0]; o.x = v0 > 0.f ? v0 : 0.f;
    float v1 = acc[4*j+1] + bup[4*j+1]; o.y = v1 > 0.f ? v1 : 0.f;
    float v2 = acc[4*j+2] + bup[4*j+2]; o.z = v2 > 0.f ? v2 : 0.f;
    float v3 = acc[4*j+3] + bup[4*j+3]; o.w = v3 > 0.f ? v3 : 0.f;
    reinterpret_cast<float4*>(dst)[j] = o;
  }
}

// ---------------------------------------------------------------------------
// cls pass 1: g[n][k] = feats[n] . Wcls[k]   (g stride 28)
// ---------------------------------------------------------------------------
__global__ __launch_bounds__(256)
void cls1_kernel(const float* __restrict__ feats, const float* __restrict__ Wcls,
                 float* __restrict__ g)
{
  const int n = blockIdx.x * 256 + threadIdx.x;
  if (blockIdx.x == 0 && threadIdx.x < 28) g[(size_t)NOUTC * 28 + threadIdx.x] = 0.f;
  const float4* src = reinterpret_cast<const float4*>(feats + (size_t)n * 64);
  float f[64];
  #pragma unroll
  for (int j = 0; j < 16; ++j) {
    float4 a = src[j];
    f[4*j+0]=a.x; f[4*j+1]=a.y; f[4*j+2]=a.z; f[4*j+3]=a.w;
  }
  #pragma unroll 1
  for (int k = 0; k < 27; ++k) {
    const float* w = Wcls + k * 64;
    float s0 = 0.f, s1 = 0.f, s2 = 0.f, s3 = 0.f;
    #pragma unroll
    for (int j = 0; j < 16; ++j) {
      s0 = fmaf(f[j],      w[j],      s0);
      s1 = fmaf(f[16 + j], w[16 + j], s1);
      s2 = fmaf(f[32 + j], w[32 + j], s2);
      s3 = fmaf(f[48 + j], w[48 + j], s3);
    }
    g[(size_t)n * 28 + k] = (s0 + s1) + (s2 + s3);
  }
}

// cls pass 2: out_cls[n] = sum_k g[nbr[k][n]][k] + bcls
__global__ __launch_bounds__(256)
void cls2_kernel(const float* __restrict__ g, const int* __restrict__ nbr,
                 const float* __restrict__ bcls, float* __restrict__ out_cls)
{
  const int n = blockIdx.x * 256 + threadIdx.x;
  float s = bcls[0];
  #pragma unroll 1
  for (int k = 0; k < 27; ++k) {
    int idx = nbr[(size_t)k * NOUTC + n];
    s += g[(size_t)idx * 28 + k];
  }
  out_cls[n] = s;
}

// ---------------------------------------------------------------------------
// init / detect / top-k select / prune
// ---------------------------------------------------------------------------
__global__ void init_kernel(uint* hist1, uint* hist2, int* tie_cnt, int* flag,
                            float* fa, float* fb, float* t0, float* t1)
{
  int i = blockIdx.x * 256 + threadIdx.x;
  if (i < 65536) hist1[i] = 0;
  else if (i < 131072) hist2[i - 65536] = 0;
  if (i == 0) { tie_cnt[0] = 0; flag[0] = 0; }
  if (i < 64) { fa[(size_t)NOUTC * 64 + i] = 0.f; fb[(size_t)NOUTC * 64 + i] = 0.f; }
  if (i < 16) { t0[(size_t)NOUTC * 16 + i] = 0.f; t1[(size_t)NOUTC * 16 + i] = 0.f; }
}

__global__ void detect_kernel(const unsigned char* __restrict__ mt, int* flag)
{
  int i = blockIdx.x * 256 + threadIdx.x;
  int p = i * 4 + 1;
  if (p < NOUTC && mt[p] != 0) flag[0] = 1;
}

__global__ void hist1_kernel(const float* __restrict__ cls, uint* __restrict__ hist)
{
  for (int i = blockIdx.x * blockDim.x + threadIdx.x; i < NOUTC; i += gridDim.x * blockDim.x)
    atomicAdd(&hist[fkey(cls[i]) >> 16], 1u);
}

__global__ void scan1_kernel(const uint* __restrict__ hist, const int* __restrict__ nums,
                             uint* __restrict__ res)
{
  __shared__ uint chunk[256];
  const int t = threadIdx.x;
  uint s = 0;
  for (int j = 0; j < 256; ++j) s += hist[t * 256 + j];
  chunk[t] = s;
  __syncthreads();
  if (t == 0) {
    uint k = (uint)nums[0];
    uint cum = 0; int c = 255;
    for (; c > 0; --c) { if (cum + chunk[c] >= k) break; cum += chunk[c]; }
    int B = c * 256; uint cum2 = cum;
    for (int b = c * 256 + 255; b >= c * 256; --b) {
      if (cum2 + hist[b] >= k) { B = b; break; }
      cum2 += hist[b];
    }
    res[0] = (uint)B; res[1] = cum2;
  }
}

__global__ void hist2_kernel(const float* __restrict__ cls, const uint* __restrict__ res1,
                             uint* __restrict__ hist)
{
  const uint B = res1[0];
  for (int i = blockIdx.x * blockDim.x + threadIdx.x; i < NOUTC; i += gridDim.x * blockDim.x) {
    uint key = fkey(cls[i]);
    if ((key >> 16) == B) atomicAdd(&hist[key & 0xffffu], 1u);
  }
}

__global__ void scan2_kernel(const uint* __restrict__ hist, const uint* __restrict__ res1,
                             const int* __restrict__ nums, uint* __restrict__ res2)
{
  __shared__ uint chunk[256];
  const int t = threadIdx.x;
  uint s = 0;
  for (int j = 0; j < 256; ++j) s += hist[t * 256 + j];
  chunk[t] = s;
  __syncthreads();
  if (t == 0) {
    uint k = (uint)nums[0];
    uint cum = res1[1]; int c = 255;
    for (; c > 0; --c) { if (cum + chunk[c] >= k) break; cum += chunk[c]; }
    int L = c * 256; uint cum2 = cum;
    for (int b = c * 256 + 255; b >= c * 256; --b) {
      if (cum2 + hist[b] >= k) { L = b; break; }
      cum2 += hist[b];
    }
    res2[0] = (res1[0] << 16) | (uint)L;
    res2[1] = k - cum2;
  }
}

__global__ void mark_kernel(const float* __restrict__ cls, const uint* __restrict__ res2,
                            unsigned char* __restrict__ msel, int* tie_cnt, int* tie_idx)
{
  const uint T = res2[0];
  for (int i = blockIdx.x * blockDim.x + threadIdx.x; i < NOUTC; i += gridDim.x * blockDim.x) {
    uint key = fkey(cls[i]);
    msel[i] = key > T ? 1 : 0;
    if (key == T) {
      int p = atomicAdd(tie_cnt, 1);
      if (p < 4096) tie_idx[p] = i;
    }
  }
}

__global__ void tie_kernel(const uint* __restrict__ res2, const int* __restrict__ tie_cnt,
                           const int* __restrict__ tie_idx, unsigned char* __restrict__ msel)
{
  int need = (int)res2[1];
  int cnt = tie_cnt[0]; if (cnt > 4096) cnt = 4096;
  if (need <= 0) return;
  if (cnt <= need) {
    for (int i = threadIdx.x; i < cnt; i += 256) msel[tie_idx[i]] = 1;
  } else {
    for (int i = threadIdx.x; i < cnt; i += 256) {
      int my = tie_idx[i];
      int rank = 0;
      for (int j = 0; j < cnt; ++j) rank += (tie_idx[j] < my) ? 1 : 0;
      if (rank < need) msel[my] = 1;
    }
  }
}

__global__ void prune_kernel(const float* __restrict__ feats, const unsigned char* __restrict__ msel,
                             const void* __restrict__ mtrue, const int* __restrict__ flag,
                             float* __restrict__ dout)
{
  const unsigned char* mb = (const unsigned char*)mtrue;
  const int* mi = (const int*)mtrue;
  const bool bytes = (flag[0] != 0);
  float* pruned = dout + NOUTC;
  float* maskf  = dout + NOUTC + (size_t)NOUTC * 64;
  const float4* src = reinterpret_cast<const float4*>(feats);
  float4* dst = reinterpret_cast<float4*>(pruned);
  const int total = NOUTC * 16;
  for (int i = blockIdx.x * blockDim.x + threadIdx.x; i < total; i += gridDim.x * blockDim.x) {
    int n = i >> 4;
    bool mt = bytes ? (mb[n] != 0) : (mi[n] != 0);
    bool m = (msel[n] != 0) || mt;
    float4 v = src[i];
    float4 z = {0.f, 0.f, 0.f, 0.f};
    dst[i] = m ? v : z;
    if ((i & 15) == 0) maskf[n] = m ? 1.f : 0.f;
  }
}

// ---------------------------------------------------------------------------
extern "C" void kernel_launch(void* const* d_in, const int* in_sizes, int n_in,
                              void* d_out, int out_size, void* d_ws, size_t ws_size,
                              hipStream_t stream)
{
  const float* x    = (const float*)d_in[0];
  const float* Wup  = (const float*)d_in[1];
  const float* bup  = (const float*)d_in[2];
  const float* Wc0  = (const float*)d_in[3];
  const float* bc0  = (const float*)d_in[4];
  const float* W00  = (const float*)d_in[5];
  const float* b00  = (const float*)d_in[6];
  const float* W01  = (const float*)d_in[7];
  const float* b01  = (const float*)d_in[8];
  const float* W10  = (const float*)d_in[9];
  const float* b10  = (const float*)d_in[10];
  const float* W11  = (const float*)d_in[11];
  const float* b11  = (const float*)d_in[12];
  const float* W12  = (const float*)d_in[13];
  const float* b12  = (const float*)d_in[14];
  const float* Wcls = (const float*)d_in[15];
  const float* bcls = (const float*)d_in[16];
  const int*   nbr  = (const int*)d_in[17];
  const void*  mtrue= d_in[18];
  const int*   nums = (const int*)d_in[19];

  float* dout = (float*)d_out;

  float* fa = (float*)d_ws;                       // (N+1)*64
  float* t0 = fa + (size_t)(NOUTC + 1) * 64;      // (N+1)*16
  float* t1 = t0 + (size_t)(NOUTC + 1) * 16;      // (N+1)*16
  float* g  = t0;                                 // (N+1)*28 overlaps t0+t1 (dead by cls time)
  uint*  hist1 = (uint*)(t1 + (size_t)(NOUTC + 1) * 16);
  uint*  hist2 = hist1 + 65536;
  uint*  res1  = hist2 + 65536;
  uint*  res2  = res1 + 2;
  int*   tie_cnt = (int*)(res2 + 2);
  int*   flag    = tie_cnt + 1;
  int*   tie_idx = flag + 1;
  unsigned char* msel = (unsigned char*)(tie_idx + 4096);
  float* fb = dout + NOUTC;   // (N+1)*64 parked in d_out's pruned+mask region

  init_kernel<<<512, 256, 0, stream>>>(hist1, hist2, tie_cnt, flag, fa, fb, t0, t1);
  detect_kernel<<<128, 256, 0, stream>>>((const unsigned char*)mtrue, flag);

  up2_kernel<<<512, 256, 0, stream>>>(x, Wup, bup, fa);
  conv_c0_kernel<<<512, 256, 0, stream>>>(fa, nbr, Wc0, bc0, fb);

  const float* cur = fb; float* nxt = fa;
  for (int i = 0; i < 3; ++i) {
    conv_A_kernel<<<512, 256, 0, stream>>>(cur, nbr,
        W00 + (size_t)i * 27 * 1024, b00 + i * 16,
        W10 + (size_t)i * 1024,      b10 + i * 16, t0, t1);
    conv_B_kernel<<<512, 256, 0, stream>>>(t0, t1, cur, nbr,
        W01 + (size_t)i * 27 * 512, b01 + i * 32,
        W11 + (size_t)i * 27 * 256, b11 + i * 16,
        W12 + (size_t)i * 512,      b12 + i * 32, nxt);
    float* tmp = (float*)cur; cur = nxt; nxt = tmp;
  }
  // final features in fa

  cls1_kernel<<<512, 256, 0, stream>>>(cur, Wcls, g);
  cls2_kernel<<<512, 256, 0, stream>>>(g, nbr, bcls, dout);

  hist1_kernel<<<512, 256, 0, stream>>>(dout, hist1);
  scan1_kernel<<<1, 256, 0, stream>>>(hist1, nums, res1);
  hist2_kernel<<<512, 256, 0, stream>>>(dout, res1, hist2);
  scan2_kernel<<<1, 256, 0, stream>>>(hist2, res1, nums, res2);
  mark_kernel<<<512, 256, 0, stream>>>(dout, res2, msel, tie_cnt, tie_idx);
  tie_kernel<<<1, 256, 0, stream>>>(res2, tie_cnt, tie_idx, msel);
  prune_kernel<<<4096, 256, 0, stream>>>(cur, msel, mtrue, flag, dout);
}

// Round 4
// 1582.474 us; speedup vs baseline: 1.6725x; 1.6725x over previous
//
#include <hip/hip_runtime.h>
#include <cstdint>

#define NOUTC 131072
#define NINC  16384

using uint = unsigned int;

__device__ __forceinline__ uint fkey(float v){
  uint u = __float_as_uint(v);
  return (u & 0x80000000u) ? ~u : (u | 0x80000000u);
}

// ---------------------------------------------------------------------------
// Transposed-weight layout offsets (floats) inside the wt buffer.
// Layout per tensor: [k][g][cin][COUT/4], g = cout-quarter.
// ---------------------------------------------------------------------------
#define OFF_WC0 0          // (27,64,64)  110592
#define OFF_W00 110592     // (81,64,16)  82944
#define OFF_W10 193536     // (3,64,16)   3072
#define OFF_W01 196608     // (81,16,32)  41472
#define OFF_W11 238080     // (81,16,16)  20736
#define OFF_W12 258816     // (3,16,32)   1536
#define OFF_WUP 260352     // (8,64,64)   32768
#define WT_TOTAL 293120

__device__ __forceinline__ void wtrans_one(const float* src, float* dst, int local,
                                           int CIN, int COUT) {
  const int CG = COUT / 4;
  int j = local % CG;
  int rest = local / CG;
  int ci = rest % CIN;
  rest /= CIN;
  int g = rest & 3;
  int k = rest >> 2;
  dst[local] = src[(k * CIN + ci) * COUT + g * CG + j];
}

__global__ __launch_bounds__(256)
void wtrans_kernel(const float* __restrict__ Wc0, const float* __restrict__ W00,
                   const float* __restrict__ W10, const float* __restrict__ W01,
                   const float* __restrict__ W11, const float* __restrict__ W12,
                   const float* __restrict__ Wup, float* __restrict__ wt)
{
  int tid = blockIdx.x * 256 + threadIdx.x;
  if (tid >= WT_TOTAL) return;
  if (tid < OFF_W00)      wtrans_one(Wc0, wt + OFF_WC0, tid - OFF_WC0, 64, 64);
  else if (tid < OFF_W10) wtrans_one(W00, wt + OFF_W00, tid - OFF_W00, 64, 16);
  else if (tid < OFF_W01) wtrans_one(W10, wt + OFF_W10, tid - OFF_W10, 64, 16);
  else if (tid < OFF_W11) wtrans_one(W01, wt + OFF_W01, tid - OFF_W01, 16, 32);
  else if (tid < OFF_W12) wtrans_one(W11, wt + OFF_W11, tid - OFF_W11, 16, 16);
  else if (tid < OFF_WUP) wtrans_one(W12, wt + OFF_W12, tid - OFF_W12, 16, 32);
  else                    wtrans_one(Wup, wt + OFF_WUP, tid - OFF_WUP, 64, 64);
}

#define UNPACK16(fr, a0, a1, a2, a3)                                   \
  fr[0]=a0.x; fr[1]=a0.y; fr[2]=a0.z; fr[3]=a0.w;                      \
  fr[4]=a1.x; fr[5]=a1.y; fr[6]=a1.z; fr[7]=a1.w;                      \
  fr[8]=a2.x; fr[9]=a2.y; fr[10]=a2.z; fr[11]=a2.w;                    \
  fr[12]=a3.x; fr[13]=a3.y; fr[14]=a3.z; fr[15]=a3.w;

// ---------------------------------------------------------------------------
// c0: 64->64, 27 taps. Block = 64 rows x 4 waves; wave g computes couts
// [g*16, g*16+16). Weights scalar-loaded from transposed slabs.
// ---------------------------------------------------------------------------
__global__ __launch_bounds__(256)
void conv_c0_v2(const float* __restrict__ feats, const int* __restrict__ nbr,
                const float* __restrict__ wt_c0, const float* __restrict__ bias,
                float* __restrict__ outp)
{
  const int gu   = __builtin_amdgcn_readfirstlane(threadIdx.x >> 6);
  const int lane = threadIdx.x & 63;
  const int n    = blockIdx.x * 64 + lane;

  float acc[16];
  #pragma unroll
  for (int i = 0; i < 16; ++i) acc[i] = 0.f;

  int idx = nbr[n];
  #pragma unroll 1
  for (int k = 0; k < 27; ++k) {
    const int nidx = (k < 26) ? nbr[(size_t)(k + 1) * NOUTC + n] : 0;
    const float4* src = reinterpret_cast<const float4*>(feats + (size_t)idx * 64);
    const float* w = wt_c0 + (size_t)(k * 4 + gu) * 1024;
    #pragma unroll
    for (int c = 0; c < 4; ++c) {
      float4 a0 = src[c*4+0], a1 = src[c*4+1], a2 = src[c*4+2], a3 = src[c*4+3];
      float fr[16]; UNPACK16(fr, a0, a1, a2, a3)
      const float* wc = w + c * 256;
      #pragma unroll
      for (int u = 0; u < 16; ++u)
        #pragma unroll
        for (int j = 0; j < 16; ++j)
          acc[j] = fmaf(fr[u], wc[u * 16 + j], acc[j]);
    }
    idx = nidx;
  }

  float* dst = outp + (size_t)n * 64 + gu * 16;
  #pragma unroll
  for (int q = 0; q < 4; ++q) {
    float4 o;
    float v0 = acc[4*q+0] + bias[gu*16 + 4*q+0]; o.x = v0 > 0.f ? v0 : 0.f;
    float v1 = acc[4*q+1] + bias[gu*16 + 4*q+1]; o.y = v1 > 0.f ? v1 : 0.f;
    float v2 = acc[4*q+2] + bias[gu*16 + 4*q+2]; o.z = v2 > 0.f ? v2 : 0.f;
    float v3 = acc[4*q+3] + bias[gu*16 + 4*q+3]; o.w = v3 > 0.f ? v3 : 0.f;
    reinterpret_cast<float4*>(dst)[q] = o;
  }
}

// ---------------------------------------------------------------------------
// A: t0 = relu(spconv(cur,W00)+b00) [64->16,27 taps], t1 = relu(cur@W10+b10).
// Wave g computes couts [g*4, g*4+4) of both.
// ---------------------------------------------------------------------------
__global__ __launch_bounds__(256)
void conv_A_v2(const float* __restrict__ feats, const int* __restrict__ nbr,
               const float* __restrict__ w00t, const float* __restrict__ b00i,
               const float* __restrict__ w10t, const float* __restrict__ b10i,
               float* __restrict__ t0, float* __restrict__ t1)
{
  const int gu   = __builtin_amdgcn_readfirstlane(threadIdx.x >> 6);
  const int lane = threadIdx.x & 63;
  const int n    = blockIdx.x * 64 + lane;

  float acc0[4], acc1[4];
  #pragma unroll
  for (int i = 0; i < 4; ++i) { acc0[i] = 0.f; acc1[i] = 0.f; }

  int idx = nbr[n];
  #pragma unroll 1
  for (int k = 0; k < 27; ++k) {
    const int nidx = (k < 26) ? nbr[(size_t)(k + 1) * NOUTC + n] : 0;
    const float4* src = reinterpret_cast<const float4*>(feats + (size_t)idx * 64);
    const float* w = w00t + (size_t)(k * 4 + gu) * 256;
    #pragma unroll
    for (int c = 0; c < 4; ++c) {
      float4 a0 = src[c*4+0], a1 = src[c*4+1], a2 = src[c*4+2], a3 = src[c*4+3];
      float fr[16]; UNPACK16(fr, a0, a1, a2, a3)
      const float* wc = w + c * 64;
      #pragma unroll
      for (int u = 0; u < 16; ++u)
        #pragma unroll
        for (int j = 0; j < 4; ++j)
          acc0[j] = fmaf(fr[u], wc[u * 4 + j], acc0[j]);
    }
    idx = nidx;
  }

  // self row @ W10 (1x1 conv)
  {
    const float4* src = reinterpret_cast<const float4*>(feats + (size_t)n * 64);
    const float* w = w10t + (size_t)gu * 256;
    #pragma unroll
    for (int c = 0; c < 4; ++c) {
      float4 a0 = src[c*4+0], a1 = src[c*4+1], a2 = src[c*4+2], a3 = src[c*4+3];
      float fr[16]; UNPACK16(fr, a0, a1, a2, a3)
      const float* wc = w + c * 64;
      #pragma unroll
      for (int u = 0; u < 16; ++u)
        #pragma unroll
        for (int j = 0; j < 4; ++j)
          acc1[j] = fmaf(fr[u], wc[u * 4 + j], acc1[j]);
    }
  }

  float4 o0, o1; float v;
  v = acc0[0] + b00i[gu*4+0]; o0.x = v > 0.f ? v : 0.f;
  v = acc0[1] + b00i[gu*4+1]; o0.y = v > 0.f ? v : 0.f;
  v = acc0[2] + b00i[gu*4+2]; o0.z = v > 0.f ? v : 0.f;
  v = acc0[3] + b00i[gu*4+3]; o0.w = v > 0.f ? v : 0.f;
  v = acc1[0] + b10i[gu*4+0]; o1.x = v > 0.f ? v : 0.f;
  v = acc1[1] + b10i[gu*4+1]; o1.y = v > 0.f ? v : 0.f;
  v = acc1[2] + b10i[gu*4+2]; o1.z = v > 0.f ? v : 0.f;
  v = acc1[3] + b10i[gu*4+3]; o1.w = v > 0.f ? v : 0.f;
  *reinterpret_cast<float4*>(t0 + (size_t)n * 16 + gu * 4) = o0;
  *reinterpret_cast<float4*>(t1 + (size_t)n * 16 + gu * 4) = o1;
}

// ---------------------------------------------------------------------------
// B: o0 = spconv(t0,W01)+b01 [16->32]; t2 = relu(spconv(t1,W11)+b11) [16->16];
//    o1 = t2@W12+b12; nxt = concat(o0,o1) + cur.
// Wave g: o0 couts [g*8,g*8+8), t2 couts [g*4,g*4+4), o1 couts [g*8,g*8+8).
// t2 shared across waves via 4KB LDS (conflict-free layout [ch][lane]).
// ---------------------------------------------------------------------------
__global__ __launch_bounds__(256)
void conv_B_v2(const float* __restrict__ t0, const float* __restrict__ t1,
               const float* __restrict__ cur, const int* __restrict__ nbr,
               const float* __restrict__ w01t, const float* __restrict__ b01i,
               const float* __restrict__ w11t, const float* __restrict__ b11i,
               const float* __restrict__ w12t, const float* __restrict__ b12i,
               float* __restrict__ nxt)
{
  __shared__ float t2s[16 * 64];
  const int gu   = __builtin_amdgcn_readfirstlane(threadIdx.x >> 6);
  const int lane = threadIdx.x & 63;
  const int n    = blockIdx.x * 64 + lane;

  float acc01[8], acc11[4];
  #pragma unroll
  for (int i = 0; i < 8; ++i) acc01[i] = 0.f;
  #pragma unroll
  for (int i = 0; i < 4; ++i) acc11[i] = 0.f;

  int idx = nbr[n];
  #pragma unroll 1
  for (int k = 0; k < 27; ++k) {
    const int nidx = (k < 26) ? nbr[(size_t)(k + 1) * NOUTC + n] : 0;
    const float4* s0 = reinterpret_cast<const float4*>(t0 + (size_t)idx * 16);
    const float4* s1 = reinterpret_cast<const float4*>(t1 + (size_t)idx * 16);
    float4 a0 = s0[0], a1 = s0[1], a2 = s0[2], a3 = s0[3];
    float4 c0 = s1[0], c1 = s1[1], c2 = s1[2], c3 = s1[3];
    float f0[16]; UNPACK16(f0, a0, a1, a2, a3)
    float f1[16]; UNPACK16(f1, c0, c1, c2, c3)
    const float* w01 = w01t + (size_t)(k * 4 + gu) * 128;
    const float* w11 = w11t + (size_t)(k * 4 + gu) * 64;
    #pragma unroll
    for (int u = 0; u < 16; ++u)
      #pragma unroll
      for (int j = 0; j < 8; ++j)
        acc01[j] = fmaf(f0[u], w01[u * 8 + j], acc01[j]);
    #pragma unroll
    for (int u = 0; u < 16; ++u)
      #pragma unroll
      for (int j = 0; j < 4; ++j)
        acc11[j] = fmaf(f1[u], w11[u * 4 + j], acc11[j]);
    idx = nidx;
  }

  // share t2 = relu(acc11 + b11) across waves
  #pragma unroll
  for (int j = 0; j < 4; ++j) {
    float v = acc11[j] + b11i[gu * 4 + j];
    t2s[(gu * 4 + j) * 64 + lane] = v > 0.f ? v : 0.f;
  }
  __syncthreads();

  float t2[16];
  #pragma unroll
  for (int u = 0; u < 16; ++u) t2[u] = t2s[u * 64 + lane];

  float o1[8];
  #pragma unroll
  for (int j = 0; j < 8; ++j) o1[j] = b12i[gu * 8 + j];
  {
    const float* w12 = w12t + (size_t)gu * 128;
    #pragma unroll
    for (int u = 0; u < 16; ++u)
      #pragma unroll
      for (int j = 0; j < 8; ++j)
        o1[j] = fmaf(t2[u], w12[u * 8 + j], o1[j]);
  }

  // epilogue: nxt = concat(o0, o1) + cur
  {
    const float* rs = cur + (size_t)n * 64 + gu * 8;
    float* dst = nxt + (size_t)n * 64 + gu * 8;
    float4 r0 = *reinterpret_cast<const float4*>(rs);
    float4 r1 = *reinterpret_cast<const float4*>(rs + 4);
    float4 s0, s1;
    s0.x = acc01[0] + b01i[gu*8+0] + r0.x;
    s0.y = acc01[1] + b01i[gu*8+1] + r0.y;
    s0.z = acc01[2] + b01i[gu*8+2] + r0.z;
    s0.w = acc01[3] + b01i[gu*8+3] + r0.w;
    s1.x = acc01[4] + b01i[gu*8+4] + r1.x;
    s1.y = acc01[5] + b01i[gu*8+5] + r1.y;
    s1.z = acc01[6] + b01i[gu*8+6] + r1.z;
    s1.w = acc01[7] + b01i[gu*8+7] + r1.w;
    *reinterpret_cast<float4*>(dst)     = s0;
    *reinterpret_cast<float4*>(dst + 4) = s1;
  }
  {
    const float* rs = cur + (size_t)n * 64 + 32 + gu * 8;
    float* dst = nxt + (size_t)n * 64 + 32 + gu * 8;
    float4 r0 = *reinterpret_cast<const float4*>(rs);
    float4 r1 = *reinterpret_cast<const float4*>(rs + 4);
    float4 s0, s1;
    s0.x = o1[0] + r0.x; s0.y = o1[1] + r0.y; s0.z = o1[2] + r0.z; s0.w = o1[3] + r0.w;
    s1.x = o1[4] + r1.x; s1.y = o1[5] + r1.y; s1.z = o1[6] + r1.z; s1.w = o1[7] + r1.w;
    *reinterpret_cast<float4*>(dst)     = s0;
    *reinterpret_cast<float4*>(dst + 4) = s1;
  }
}

// ---------------------------------------------------------------------------
// upsample: fa[(n*8+k)*64+:] = relu(x[n]@Wup[k]+bup). k uniform per block,
// wave g computes couts [g*16,g*16+16).
// ---------------------------------------------------------------------------
__global__ __launch_bounds__(256)
void up2_v2(const float* __restrict__ x, const float* __restrict__ wt_up,
            const float* __restrict__ bup, float* __restrict__ outp)
{
  const int gu   = __builtin_amdgcn_readfirstlane(threadIdx.x >> 6);
  const int lane = threadIdx.x & 63;
  const int k    = blockIdx.x & 7;
  const int n    = (blockIdx.x >> 3) * 64 + lane;

  float acc[16];
  #pragma unroll
  for (int i = 0; i < 16; ++i) acc[i] = 0.f;

  const float4* src = reinterpret_cast<const float4*>(x + (size_t)n * 64);
  const float* w = wt_up + (size_t)(k * 4 + gu) * 1024;
  #pragma unroll
  for (int c = 0; c < 4; ++c) {
    float4 a0 = src[c*4+0], a1 = src[c*4+1], a2 = src[c*4+2], a3 = src[c*4+3];
    float fr[16]; UNPACK16(fr, a0, a1, a2, a3)
    const float* wc = w + c * 256;
    #pragma unroll
    for (int u = 0; u < 16; ++u)
      #pragma unroll
      for (int j = 0; j < 16; ++j)
        acc[j] = fmaf(fr[u], wc[u * 16 + j], acc[j]);
  }

  float* dst = outp + ((size_t)n * 8 + k) * 64 + gu * 16;
  #pragma unroll
  for (int q = 0; q < 4; ++q) {
    float4 o;
    float v0 = acc[4*q+0] + bup[gu*16 + 4*q+0]; o.x = v0 > 0.f ? v0 : 0.f;
    float v1 = acc[4*q+1] + bup[gu*16 + 4*q+1]; o.y = v1 > 0.f ? v1 : 0.f;
    float v2 = acc[4*q+2] + bup[gu*16 + 4*q+2]; o.z = v2 > 0.f ? v2 : 0.f;
    float v3 = acc[4*q+3] + bup[gu*16 + 4*q+3]; o.w = v3 > 0.f ? v3 : 0.f;
    reinterpret_cast<float4*>(dst)[q] = o;
  }
}

// ---------------------------------------------------------------------------
// cls pass 1: g[n][k] = feats[n] . Wcls[k]
// ---------------------------------------------------------------------------
__global__ __launch_bounds__(256)
void cls1_kernel(const float* __restrict__ feats, const float* __restrict__ Wcls,
                 float* __restrict__ g)
{
  const int n = blockIdx.x * 256 + threadIdx.x;
  if (blockIdx.x == 0 && threadIdx.x < 28) g[(size_t)NOUTC * 28 + threadIdx.x] = 0.f;
  const float4* src = reinterpret_cast<const float4*>(feats + (size_t)n * 64);
  float f[64];
  #pragma unroll
  for (int j = 0; j < 16; ++j) {
    float4 a = src[j];
    f[4*j+0]=a.x; f[4*j+1]=a.y; f[4*j+2]=a.z; f[4*j+3]=a.w;
  }
  #pragma unroll 1
  for (int k = 0; k < 27; ++k) {
    const float* w = Wcls + k * 64;
    float s0 = 0.f, s1 = 0.f, s2 = 0.f, s3 = 0.f;
    #pragma unroll
    for (int j = 0; j < 16; ++j) {
      s0 = fmaf(f[j],      w[j],      s0);
      s1 = fmaf(f[16 + j], w[16 + j], s1);
      s2 = fmaf(f[32 + j], w[32 + j], s2);
      s3 = fmaf(f[48 + j], w[48 + j], s3);
    }
    g[(size_t)n * 28 + k] = (s0 + s1) + (s2 + s3);
  }
}

__global__ __launch_bounds__(256)
void cls2_kernel(const float* __restrict__ g, const int* __restrict__ nbr,
                 const float* __restrict__ bcls, float* __restrict__ out_cls)
{
  const int n = blockIdx.x * 256 + threadIdx.x;
  float s = bcls[0];
  #pragma unroll 1
  for (int k = 0; k < 27; ++k) {
    int idx = nbr[(size_t)k * NOUTC + n];
    s += g[(size_t)idx * 28 + k];
  }
  out_cls[n] = s;
}

// ---------------------------------------------------------------------------
// init / detect / top-k select / prune
// ---------------------------------------------------------------------------
__global__ void init_kernel(uint* hist1, uint* hist2, int* tie_cnt, int* flag,
                            float* fa, float* fb, float* t0, float* t1)
{
  int i = blockIdx.x * 256 + threadIdx.x;
  if (i < 65536) hist1[i] = 0;
  else if (i < 131072) hist2[i - 65536] = 0;
  if (i == 0) { tie_cnt[0] = 0; flag[0] = 0; }
  if (i < 64) { fa[(size_t)NOUTC * 64 + i] = 0.f; fb[(size_t)NOUTC * 64 + i] = 0.f; }
  if (i < 16) { t0[(size_t)NOUTC * 16 + i] = 0.f; t1[(size_t)NOUTC * 16 + i] = 0.f; }
}

__global__ void detect_kernel(const unsigned char* __restrict__ mt, int* flag)
{
  int i = blockIdx.x * 256 + threadIdx.x;
  int p = i * 4 + 1;
  if (p < NOUTC && mt[p] != 0) flag[0] = 1;
}

__global__ void hist1_kernel(const float* __restrict__ cls, uint* __restrict__ hist)
{
  for (int i = blockIdx.x * blockDim.x + threadIdx.x; i < NOUTC; i += gridDim.x * blockDim.x)
    atomicAdd(&hist[fkey(cls[i]) >> 16], 1u);
}

__global__ void scan1_kernel(const uint* __restrict__ hist, const int* __restrict__ nums,
                             uint* __restrict__ res)
{
  __shared__ uint chunk[256];
  const int t = threadIdx.x;
  uint s = 0;
  for (int j = 0; j < 256; ++j) s += hist[t * 256 + j];
  chunk[t] = s;
  __syncthreads();
  if (t == 0) {
    uint k = (uint)nums[0];
    uint cum = 0; int c = 255;
    for (; c > 0; --c) { if (cum + chunk[c] >= k) break; cum += chunk[c]; }
    int B = c * 256; uint cum2 = cum;
    for (int b = c * 256 + 255; b >= c * 256; --b) {
      if (cum2 + hist[b] >= k) { B = b; break; }
      cum2 += hist[b];
    }
    res[0] = (uint)B; res[1] = cum2;
  }
}

__global__ void hist2_kernel(const float* __restrict__ cls, const uint* __restrict__ res1,
                             uint* __restrict__ hist)
{
  const uint B = res1[0];
  for (int i = blockIdx.x * blockDim.x + threadIdx.x; i < NOUTC; i += gridDim.x * blockDim.x) {
    uint key = fkey(cls[i]);
    if ((key >> 16) == B) atomicAdd(&hist[key & 0xffffu], 1u);
  }
}

__global__ void scan2_kernel(const uint* __restrict__ hist, const uint* __restrict__ res1,
                             const int* __restrict__ nums, uint* __restrict__ res2)
{
  __shared__ uint chunk[256];
  const int t = threadIdx.x;
  uint s = 0;
  for (int j = 0; j < 256; ++j) s += hist[t * 256 + j];
  chunk[t] = s;
  __syncthreads();
  if (t == 0) {
    uint k = (uint)nums[0];
    uint cum = res1[1]; int c = 255;
    for (; c > 0; --c) { if (cum + chunk[c] >= k) break; cum += chunk[c]; }
    int L = c * 256; uint cum2 = cum;
    for (int b = c * 256 + 255; b >= c * 256; --b) {
      if (cum2 + hist[b] >= k) { L = b; break; }
      cum2 += hist[b];
    }
    res2[0] = (res1[0] << 16) | (uint)L;
    res2[1] = k - cum2;
  }
}

__global__ void mark_kernel(const float* __restrict__ cls, const uint* __restrict__ res2,
                            unsigned char* __restrict__ msel, int* tie_cnt, int* tie_idx)
{
  const uint T = res2[0];
  for (int i = blockIdx.x * blockDim.x + threadIdx.x; i < NOUTC; i += gridDim.x * blockDim.x) {
    uint key = fkey(cls[i]);
    msel[i] = key > T ? 1 : 0;
    if (key == T) {
      int p = atomicAdd(tie_cnt, 1);
      if (p < 4096) tie_idx[p] = i;
    }
  }
}

__global__ void tie_kernel(const uint* __restrict__ res2, const int* __restrict__ tie_cnt,
                           const int* __restrict__ tie_idx, unsigned char* __restrict__ msel)
{
  int need = (int)res2[1];
  int cnt = tie_cnt[0]; if (cnt > 4096) cnt = 4096;
  if (need <= 0) return;
  if (cnt <= need) {
    for (int i = threadIdx.x; i < cnt; i += 256) msel[tie_idx[i]] = 1;
  } else {
    for (int i = threadIdx.x; i < cnt; i += 256) {
      int my = tie_idx[i];
      int rank = 0;
      for (int j = 0; j < cnt; ++j) rank += (tie_idx[j] < my) ? 1 : 0;
      if (rank < need) msel[my] = 1;
    }
  }
}

__global__ void prune_kernel(const float* __restrict__ feats, const unsigned char* __restrict__ msel,
                             const void* __restrict__ mtrue, const int* __restrict__ flag,
                             float* __restrict__ dout)
{
  const unsigned char* mb = (const unsigned char*)mtrue;
  const int* mi = (const int*)mtrue;
  const bool bytes = (flag[0] != 0);
  float* pruned = dout + NOUTC;
  float* maskf  = dout + NOUTC + (size_t)NOUTC * 64;
  const float4* src = reinterpret_cast<const float4*>(feats);
  float4* dst = reinterpret_cast<float4*>(pruned);
  const int total = NOUTC * 16;
  for (int i = blockIdx.x * blockDim.x + threadIdx.x; i < total; i += gridDim.x * blockDim.x) {
    int n = i >> 4;
    bool mt = bytes ? (mb[n] != 0) : (mi[n] != 0);
    bool m = (msel[n] != 0) || mt;
    float4 v = src[i];
    float4 z = {0.f, 0.f, 0.f, 0.f};
    dst[i] = m ? v : z;
    if ((i & 15) == 0) maskf[n] = m ? 1.f : 0.f;
  }
}

// ---------------------------------------------------------------------------
extern "C" void kernel_launch(void* const* d_in, const int* in_sizes, int n_in,
                              void* d_out, int out_size, void* d_ws, size_t ws_size,
                              hipStream_t stream)
{
  const float* x    = (const float*)d_in[0];
  const float* Wup  = (const float*)d_in[1];
  const float* bup  = (const float*)d_in[2];
  const float* Wc0  = (const float*)d_in[3];
  const float* bc0  = (const float*)d_in[4];
  const float* W00  = (const float*)d_in[5];
  const float* b00  = (const float*)d_in[6];
  const float* W01  = (const float*)d_in[7];
  const float* b01  = (const float*)d_in[8];
  const float* W10  = (const float*)d_in[9];
  const float* b10  = (const float*)d_in[10];
  const float* W11  = (const float*)d_in[11];
  const float* b11  = (const float*)d_in[12];
  const float* W12  = (const float*)d_in[13];
  const float* b12  = (const float*)d_in[14];
  const float* Wcls = (const float*)d_in[15];
  const float* bcls = (const float*)d_in[16];
  const int*   nbr  = (const int*)d_in[17];
  const void*  mtrue= d_in[18];
  const int*   nums = (const int*)d_in[19];

  float* dout = (float*)d_out;

  float* fa = (float*)d_ws;                       // (N+1)*64
  float* t0 = fa + (size_t)(NOUTC + 1) * 64;      // (N+1)*16
  float* t1 = t0 + (size_t)(NOUTC + 1) * 16;      // (N+1)*16
  float* g  = t0;                                 // (N+1)*28 overlaps t0+t1 (dead by cls time)
  uint*  hist1 = (uint*)(t1 + (size_t)(NOUTC + 1) * 16);
  uint*  hist2 = hist1 + 65536;
  uint*  res1  = hist2 + 65536;
  uint*  res2  = res1 + 2;
  int*   tie_cnt = (int*)(res2 + 2);
  int*   flag    = tie_cnt + 1;
  int*   tie_idx = flag + 1;
  unsigned char* msel = (unsigned char*)(tie_idx + 4096);
  float* wt = (float*)(msel + NOUTC);             // WT_TOTAL floats
  float* fb = dout + NOUTC;   // (N+1)*64 parked in d_out's pruned+mask region

  init_kernel<<<512, 256, 0, stream>>>(hist1, hist2, tie_cnt, flag, fa, fb, t0, t1);
  detect_kernel<<<128, 256, 0, stream>>>((const unsigned char*)mtrue, flag);
  wtrans_kernel<<<(WT_TOTAL + 255) / 256, 256, 0, stream>>>(
      Wc0, W00, W10, W01, W11, W12, Wup, wt);

  up2_v2<<<2048, 256, 0, stream>>>(x, wt + OFF_WUP, bup, fa);
  conv_c0_v2<<<2048, 256, 0, stream>>>(fa, nbr, wt + OFF_WC0, bc0, fb);

  const float* cur = fb; float* nxt = fa;
  for (int i = 0; i < 3; ++i) {
    conv_A_v2<<<2048, 256, 0, stream>>>(cur, nbr,
        wt + OFF_W00 + (size_t)i * 27 * 1024, b00 + i * 16,
        wt + OFF_W10 + (size_t)i * 1024,      b10 + i * 16, t0, t1);
    conv_B_v2<<<2048, 256, 0, stream>>>(t0, t1, cur, nbr,
        wt + OFF_W01 + (size_t)i * 27 * 512, b01 + i * 32,
        wt + OFF_W11 + (size_t)i * 27 * 256, b11 + i * 16,
        wt + OFF_W12 + (size_t)i * 512,      b12 + i * 32, nxt);
    float* tmp = (float*)cur; cur = nxt; nxt = tmp;
  }
  // final features in fa

  cls1_kernel<<<512, 256, 0, stream>>>(cur, Wcls, g);
  cls2_kernel<<<512, 256, 0, stream>>>(g, nbr, bcls, dout);

  hist1_kernel<<<512, 256, 0, stream>>>(dout, hist1);
  scan1_kernel<<<1, 256, 0, stream>>>(hist1, nums, res1);
  hist2_kernel<<<512, 256, 0, stream>>>(dout, res1, hist2);
  scan2_kernel<<<1, 256, 0, stream>>>(hist2, res1, nums, res2);
  mark_kernel<<<512, 256, 0, stream>>>(dout, res2, msel, tie_cnt, tie_idx);
  tie_kernel<<<1, 256, 0, stream>>>(res2, tie_cnt, tie_idx, msel);
  prune_kernel<<<4096, 256, 0, stream>>>(cur, msel, mtrue, flag, dout);
}